// Round 2
// baseline (165.817 us; speedup 1.0000x reference)
//
#include <hip/hip_runtime.h>

// StructureTensorEffect: B=4, C=3, H=W=1024, fp32.
// Round 2: vertical-reuse streaming. Each thread owns 8 consecutive rows of
// one column. For non-integer sigma: im=-(ip+1), fm=1-fp, ip in {0,1,2}.
// Per shared row r compute hm(r),hp(r),cc(r); outputs are linear in these,
// scatter into per-pixel su/sv with wave-uniform coefficients.
// Loads: 72/pixel -> ~23/pixel (VMEM-issue was the round-1 bottleneck).

#define W_ 1024
#define H_ 1024
#define PLANE (1 << 20)

__device__ __forceinline__ float lerp1(float a, float b, float f) {
    return fmaf(f, b - a, a);
}

// Generic per-pixel path (borders + any sigma) — verified in round 1.
__device__ void slow_pixel(const float* __restrict__ Xb, float* __restrict__ Ob,
                           float sg, int xi, int y)
{
    float imf = floorf(-sg), ipf = floorf(sg);
    float fm  = -sg - imf;
    float fp  =  sg - ipf;
    int   im  = (int)imf, ip = (int)ipf;

    int cm0 = min(max(xi + im, 0), W_ - 1), cm1 = min(cm0 + 1, W_ - 1);
    int cp0 = min(max(xi + ip, 0), W_ - 1), cp1 = min(cp0 + 1, W_ - 1);
    int rm0 = min(max(y + im, 0), H_ - 1),  rm1 = min(rm0 + 1, H_ - 1);
    int rp0 = min(max(y + ip, 0), H_ - 1),  rp1 = min(rp0 + 1, H_ - 1);

    int o_rm0 = rm0 << 10, o_rm1 = rm1 << 10;
    int o_rp0 = rp0 << 10, o_rp1 = rp1 << 10;
    int o_r0  = y   << 10;

    float oxx = 0.f, oyy = 0.f, oxy = 0.f;

    #pragma unroll
    for (int c = 0; c < 3; ++c) {
        const float* base = Xb + ((size_t)c << 20);

        float hm_m0 = lerp1(base[o_rm0 + cm0], base[o_rm0 + cm1], fm);
        float hm_m1 = lerp1(base[o_rm1 + cm0], base[o_rm1 + cm1], fm);
        float hm_0  = lerp1(base[o_r0  + cm0], base[o_r0  + cm1], fm);
        float hm_p0 = lerp1(base[o_rp0 + cm0], base[o_rp0 + cm1], fm);
        float hm_p1 = lerp1(base[o_rp1 + cm0], base[o_rp1 + cm1], fm);
        float hp_m0 = lerp1(base[o_rm0 + cp0], base[o_rm0 + cp1], fp);
        float hp_m1 = lerp1(base[o_rm1 + cp0], base[o_rm1 + cp1], fp);
        float hp_0  = lerp1(base[o_r0  + cp0], base[o_r0  + cp1], fp);
        float hp_p0 = lerp1(base[o_rp0 + cp0], base[o_rp0 + cp1], fp);
        float hp_p1 = lerp1(base[o_rp1 + cp0], base[o_rp1 + cp1], fp);
        float h0_m0 = base[o_rm0 + xi], h0_m1 = base[o_rm1 + xi];
        float h0_p0 = base[o_rp0 + xi], h0_p1 = base[o_rp1 + xi];

        float t0 = lerp1(hm_m0, hm_m1, fm);
        float t1 = hm_0;
        float t2 = lerp1(hm_p0, hm_p1, fp);
        float t3 = lerp1(h0_m0, h0_m1, fm);
        float t4 = lerp1(h0_p0, h0_p1, fp);
        float t5 = lerp1(hp_m0, hp_m1, fm);
        float t6 = hp_0;
        float t7 = lerp1(hp_p0, hp_p1, fp);

        float su = 0.25f * (t5 + t7 - t0 - t2) + 0.5f * (t6 - t1);
        float sv = 0.25f * (t2 + t7 - t0 - t5) + 0.5f * (t4 - t3);

        float l2 = (c == 0) ? 10000.f : 1.f;
        oxx = fmaf(l2 * su, su, oxx);
        oyy = fmaf(l2 * sv, sv, oyy);
        oxy = fmaf(l2 * su, sv, oxy);
    }

    int pix = (y << 10) | xi;
    Ob[pix]             = oxx;
    Ob[PLANE + pix]     = oyy;
    Ob[2 * PLANE + pix] = oxy;
}

// Fast path: im = -(IP+1), ip = IP, fm = 1-fp, all rows interior.
// Thread owns column x, rows y0..y0+7. Shared-row streaming.
template<int IP>
__device__ void fast8(const float* __restrict__ Xb, float* __restrict__ Ob,
                      float sg, int x, int y0)
{
    constexpr int D  = 2 * IP + 3;   // coefficient window: d = -(IP+1)..IP+1
    constexpr int RW = 10 + 2 * IP;  // shared rows: y0-IP-1 .. y0+8+IP

    float fp = sg - (float)IP;       // frac of +sigma class
    float fm = 1.0f - fp;            // frac of -sigma class

    // per-offset coefficients (wave-uniform):
    //   su += cu[j]*(hp-hm);  sv += cv[j]*(hm+hp) + cw[j]*cc
    float cu[D], cv[D], cw[D];
    #pragma unroll
    for (int j = 0; j < D; ++j) { cu[j] = 0.f; cv[j] = 0.f; cw[j] = 0.f; }
    // d = im: row weight (1-fm) = fp
    cu[0]        += 0.25f * fp; cv[0]        -= 0.25f * fp; cw[0]        -= 0.5f * fp;
    // d = im+1: row weight fm
    cu[1]        += 0.25f * fm; cv[1]        -= 0.25f * fm; cw[1]        -= 0.5f * fm;
    // d = 0 (center row, taps t1/t6)
    cu[IP + 1]   += 0.5f;
    // d = ip: row weight (1-fp) = fm
    cu[2*IP + 1] += 0.25f * fm; cv[2*IP + 1] += 0.25f * fm; cw[2*IP + 1] += 0.5f * fm;
    // d = ip+1: row weight fp
    cu[2*IP + 2] += 0.25f * fp; cv[2*IP + 2] += 0.25f * fp; cw[2*IP + 2] += 0.5f * fp;

    // clamped columns (reused for every row & channel)
    int cm0 = max(x - (IP + 1), 0);
    int cm1 = cm0 + 1;                    // cm0 <= 1022 always
    int cp0 = min(x + IP, W_ - 1);
    int cp1 = min(cp0 + 1, W_ - 1);

    float oxx[8], oyy[8], oxy[8];
    #pragma unroll
    for (int k = 0; k < 8; ++k) { oxx[k] = 0.f; oyy[k] = 0.f; oxy[k] = 0.f; }

    #pragma unroll
    for (int c = 0; c < 3; ++c) {
        const float* base = Xb + ((size_t)c << 20) + ((y0 - IP - 1) << 10);
        float su[8], sv[8];
        #pragma unroll
        for (int k = 0; k < 8; ++k) { su[k] = 0.f; sv[k] = 0.f; }

        #pragma unroll
        for (int w = 0; w < RW; ++w) {
            const float* rp = base + (w << 10);
            float a0 = rp[cm0], a1 = rp[cm1];
            float b0 = rp[cp0], b1 = rp[cp1];
            float cc = rp[x];
            float hm = lerp1(a0, a1, fm);
            float hp = lerp1(b0, b1, fp);
            float q = hp - hm;
            float s = hm + hp;
            #pragma unroll
            for (int j = 0; j < D; ++j) {
                int k = w - j;               // pixel index (compile-time pruned)
                if (k >= 0 && k < 8) {
                    su[k] = fmaf(cu[j], q, su[k]);
                    sv[k] = fmaf(cv[j], s, sv[k]);
                    sv[k] = fmaf(cw[j], cc, sv[k]);
                }
            }
        }

        float l2 = (c == 0) ? 10000.f : 1.f;
        #pragma unroll
        for (int k = 0; k < 8; ++k) {
            oxx[k] = fmaf(l2 * su[k], su[k], oxx[k]);
            oyy[k] = fmaf(l2 * sv[k], sv[k], oyy[k]);
            oxy[k] = fmaf(l2 * su[k], sv[k], oxy[k]);
        }
    }

    #pragma unroll
    for (int k = 0; k < 8; ++k) {
        int pix = ((y0 + k) << 10) | x;
        Ob[pix]             = oxx[k];
        Ob[PLANE + pix]     = oyy[k];
        Ob[2 * PLANE + pix] = oxy[k];
    }
}

__global__ __launch_bounds__(256, 4) void st_kernel(
    const float* __restrict__ X, const float* __restrict__ S,
    float* __restrict__ O)
{
    int x  = blockIdx.x * 256 + threadIdx.x;
    int y0 = blockIdx.y * 8;
    int b  = blockIdx.z;

    const float* Xb = X + (size_t)b * 3 * PLANE;
    float*       Ob = O + (size_t)b * 3 * PLANE;
    float sg = S[b];

    int ip = (int)floorf(sg);
    int im = (int)floorf(-sg);
    bool sig_ok = (im == -ip - 1) && ip >= 0 && ip <= 2;
    bool fast   = sig_ok && (y0 - ip - 1 >= 0) && (y0 + 8 + ip <= H_ - 1);

    if (fast) {
        switch (ip) {
            case 0:  fast8<0>(Xb, Ob, sg, x, y0); break;
            case 1:  fast8<1>(Xb, Ob, sg, x, y0); break;
            default: fast8<2>(Xb, Ob, sg, x, y0); break;
        }
    } else {
        for (int k = 0; k < 8; ++k)
            slow_pixel(Xb, Ob, sg, x, y0 + k);
    }
}

extern "C" void kernel_launch(void* const* d_in, const int* in_sizes, int n_in,
                              void* d_out, int out_size, void* d_ws, size_t ws_size,
                              hipStream_t stream) {
    const float* x     = (const float*)d_in[0];
    const float* sigma = (const float*)d_in[1];
    float* out = (float*)d_out;

    dim3 grid(W_ / 256, H_ / 8, 4), block(256);
    hipLaunchKernelGGL(st_kernel, grid, block, 0, stream, x, sigma, out);
}

// Round 3
// 117.950 us; speedup vs baseline: 1.4058x; 1.4058x over previous
//
#include <hip/hip_runtime.h>

// StructureTensorEffect: B=4, C=3, H=W=1024, fp32.
// Round 3: vertical-reuse streaming, ROWS=4/thread, 64x4 thread block
// (64x16 pixel tile -> row refetch 1.3x), lean register scheme (no coeff
// arrays; 4 products/row + constant-index accumulate). Round 2 spilled
// (WRITE_SIZE 172MB) -- this keeps live state ~50 VGPRs.

#define W_ 1024
#define H_ 1024
#define PLANE (1 << 20)
#define ROWS 4

__device__ __forceinline__ float lerp1(float a, float b, float f) {
    return fmaf(f, b - a, a);
}

// Generic per-pixel path (borders + any sigma) — verified in rounds 1-2.
__device__ void slow_pixel(const float* __restrict__ Xb, float* __restrict__ Ob,
                           float sg, int xi, int y)
{
    float imf = floorf(-sg), ipf = floorf(sg);
    float fm  = -sg - imf;
    float fp  =  sg - ipf;
    int   im  = (int)imf, ip = (int)ipf;

    int cm0 = min(max(xi + im, 0), W_ - 1), cm1 = min(cm0 + 1, W_ - 1);
    int cp0 = min(max(xi + ip, 0), W_ - 1), cp1 = min(cp0 + 1, W_ - 1);
    int rm0 = min(max(y + im, 0), H_ - 1),  rm1 = min(rm0 + 1, H_ - 1);
    int rp0 = min(max(y + ip, 0), H_ - 1),  rp1 = min(rp0 + 1, H_ - 1);

    int o_rm0 = rm0 << 10, o_rm1 = rm1 << 10;
    int o_rp0 = rp0 << 10, o_rp1 = rp1 << 10;
    int o_r0  = y   << 10;

    float oxx = 0.f, oyy = 0.f, oxy = 0.f;

    #pragma unroll
    for (int c = 0; c < 3; ++c) {
        const float* base = Xb + ((size_t)c << 20);

        float hm_m0 = lerp1(base[o_rm0 + cm0], base[o_rm0 + cm1], fm);
        float hm_m1 = lerp1(base[o_rm1 + cm0], base[o_rm1 + cm1], fm);
        float hm_0  = lerp1(base[o_r0  + cm0], base[o_r0  + cm1], fm);
        float hm_p0 = lerp1(base[o_rp0 + cm0], base[o_rp0 + cm1], fm);
        float hm_p1 = lerp1(base[o_rp1 + cm0], base[o_rp1 + cm1], fm);
        float hp_m0 = lerp1(base[o_rm0 + cp0], base[o_rm0 + cp1], fp);
        float hp_m1 = lerp1(base[o_rm1 + cp0], base[o_rm1 + cp1], fp);
        float hp_0  = lerp1(base[o_r0  + cp0], base[o_r0  + cp1], fp);
        float hp_p0 = lerp1(base[o_rp0 + cp0], base[o_rp0 + cp1], fp);
        float hp_p1 = lerp1(base[o_rp1 + cp0], base[o_rp1 + cp1], fp);
        float h0_m0 = base[o_rm0 + xi], h0_m1 = base[o_rm1 + xi];
        float h0_p0 = base[o_rp0 + xi], h0_p1 = base[o_rp1 + xi];

        float t0 = lerp1(hm_m0, hm_m1, fm);
        float t1 = hm_0;
        float t2 = lerp1(hm_p0, hm_p1, fp);
        float t3 = lerp1(h0_m0, h0_m1, fm);
        float t4 = lerp1(h0_p0, h0_p1, fp);
        float t5 = lerp1(hp_m0, hp_m1, fm);
        float t6 = hp_0;
        float t7 = lerp1(hp_p0, hp_p1, fp);

        float su = 0.25f * (t5 + t7 - t0 - t2) + 0.5f * (t6 - t1);
        float sv = 0.25f * (t2 + t7 - t0 - t5) + 0.5f * (t4 - t3);

        float l2 = (c == 0) ? 10000.f : 1.f;
        oxx = fmaf(l2 * su, su, oxx);
        oyy = fmaf(l2 * sv, sv, oyy);
        oxy = fmaf(l2 * su, sv, oxy);
    }

    int pix = (y << 10) | xi;
    Ob[pix]             = oxx;
    Ob[PLANE + pix]     = oyy;
    Ob[2 * PLANE + pix] = oxy;
}

template<int N>
__device__ __forceinline__ void acc(float (&arr)[N], int k, float val) {
    if (k >= 0 && k < N) arr[k] += val;   // k is constant after unroll
}

// Fast path: im = -(IP+1), ip = IP, fm = 1-fp, all rows interior.
// Thread owns column x, rows y0..y0+ROWS-1.
// Per shared row w: A=0.25*(hp-hm), B=0.25*(hm+hp)+0.5*cc, hq=0.5*(hp-hm).
//   su[w]      += fp*A   sv[w]      -= fp*B     (d=im,   row-wt fp)
//   su[w-1]    += fm*A   sv[w-1]    -= fm*B     (d=im+1, row-wt fm)
//   su[w-IP-1] += hq                            (d=0, center taps)
//   su[w-2IP-1]+= fm*A   sv[w-2IP-1]+= fm*B     (d=ip,   row-wt fm)
//   su[w-2IP-2]+= fp*A   sv[w-2IP-2]+= fp*B     (d=ip+1, row-wt fp)
template<int IP>
__device__ void fast4(const float* __restrict__ Xb, float* __restrict__ Ob,
                      float fp, float fm, int x, int y0)
{
    constexpr int RW = ROWS + 2 * IP + 2;   // shared rows y0-IP-1 .. y0+ROWS+IP

    int cm0 = max(x - (IP + 1), 0);
    int cm1 = cm0 + 1;                      // cm0 <= 1022 always
    int cp0 = min(x + IP, W_ - 1);
    int cp1 = min(cp0 + 1, W_ - 1);

    float oxx[ROWS], oyy[ROWS], oxy[ROWS];
    #pragma unroll
    for (int k = 0; k < ROWS; ++k) { oxx[k] = 0.f; oyy[k] = 0.f; oxy[k] = 0.f; }

    #pragma unroll
    for (int c = 0; c < 3; ++c) {
        const float* base = Xb + ((size_t)c << 20) + ((y0 - IP - 1) << 10);
        float su[ROWS], sv[ROWS];
        #pragma unroll
        for (int k = 0; k < ROWS; ++k) { su[k] = 0.f; sv[k] = 0.f; }

        #pragma unroll
        for (int w = 0; w < RW; ++w) {
            const float* rp = base + (w << 10);
            float a0 = rp[cm0], a1 = rp[cm1];
            float b0 = rp[cp0], b1 = rp[cp1];
            float cc = rp[x];
            float hm = lerp1(a0, a1, fm);
            float hp = lerp1(b0, b1, fp);
            float q  = hp - hm;
            float A  = 0.25f * q;
            float hq = 0.5f  * q;
            float Bv = fmaf(0.25f, hm + hp, 0.5f * cc);
            float fpA = fp * A, fmA = fm * A;
            float fpB = fp * Bv, fmB = fm * Bv;

            acc(su, w,              fpA);
            acc(su, w - 1,          fmA);
            acc(su, w - IP - 1,     hq);
            acc(su, w - 2*IP - 1,   fmA);
            acc(su, w - 2*IP - 2,   fpA);
            acc(sv, w,             -fpB);
            acc(sv, w - 1,         -fmB);
            acc(sv, w - 2*IP - 1,   fmB);
            acc(sv, w - 2*IP - 2,   fpB);
        }

        float l2 = (c == 0) ? 10000.f : 1.f;
        #pragma unroll
        for (int k = 0; k < ROWS; ++k) {
            oxx[k] = fmaf(l2 * su[k], su[k], oxx[k]);
            oyy[k] = fmaf(l2 * sv[k], sv[k], oyy[k]);
            oxy[k] = fmaf(l2 * su[k], sv[k], oxy[k]);
        }
    }

    #pragma unroll
    for (int k = 0; k < ROWS; ++k) {
        int pix = ((y0 + k) << 10) | x;
        Ob[pix]             = oxx[k];
        Ob[PLANE + pix]     = oyy[k];
        Ob[2 * PLANE + pix] = oxy[k];
    }
}

// block = (64,4): 64 columns x 4 thread-rows, each thread ROWS=4 rows
// -> 64x16 pixel tile. Wave (64 lanes) = one thread-row: fast/slow branch
// is wave-uniform, loads 64-lane coalesced.
__global__ __launch_bounds__(256) void st_kernel(
    const float* __restrict__ X, const float* __restrict__ S,
    float* __restrict__ O)
{
    int x  = blockIdx.x * 64 + threadIdx.x;
    int y0 = blockIdx.y * 16 + threadIdx.y * ROWS;
    int b  = blockIdx.z;

    const float* Xb = X + (size_t)b * 3 * PLANE;
    float*       Ob = O + (size_t)b * 3 * PLANE;
    float sg = S[b];

    int ip = (int)floorf(sg);
    int im = (int)floorf(-sg);
    bool sig_ok = (im == -ip - 1) && ip >= 0 && ip <= 2;
    bool fast   = sig_ok && (y0 - ip - 1 >= 0) && (y0 + ROWS + ip <= H_ - 1);

    float fp = sg - (float)ip;
    float fm = 1.0f - fp;

    if (fast) {
        switch (ip) {
            case 0:  fast4<0>(Xb, Ob, fp, fm, x, y0); break;
            case 1:  fast4<1>(Xb, Ob, fp, fm, x, y0); break;
            default: fast4<2>(Xb, Ob, fp, fm, x, y0); break;
        }
    } else {
        for (int k = 0; k < ROWS; ++k)
            slow_pixel(Xb, Ob, sg, x, y0 + k);
    }
}

extern "C" void kernel_launch(void* const* d_in, const int* in_sizes, int n_in,
                              void* d_out, int out_size, void* d_ws, size_t ws_size,
                              hipStream_t stream) {
    const float* x     = (const float*)d_in[0];
    const float* sigma = (const float*)d_in[1];
    float* out = (float*)d_out;

    dim3 grid(W_ / 64, H_ / 16, 4), block(64, 4);
    hipLaunchKernelGGL(st_kernel, grid, block, 0, stream, x, sigma, out);
}